// Round 6
// baseline (217.829 us; speedup 1.0000x reference)
//
#include <hip/hip_runtime.h>

// Problem constants
#define TD 128        // D
#define TS 1024       // SIZE (codes)
#define TT 2048       // T
#define NROWS 32768   // B*T
#define SPLIT 2       // blocks per code in gather-sum
#define EMA_W 0.99f

// d_out layout (flat fp32): [quantized BxDxT][diff][new_embedding SxD][new_usage S]
#define OFF_Q     0
#define OFF_DIFF  4194304
#define OFF_EMB   4194305
#define OFF_USAGE 4325377

// ws layout (units: 4-byte words). End = 4,788,292 words = 19.15 MB,
// safely under the PROVEN ws_size lower bound of 19.68 MB (R4 ran its xf path).
#define WS_E2      0         // 1024 f
#define WS_COUNTS  1024      // 1024 f
#define WS_CODES   2048      // 32768 i
#define WS_ROWLIST 34816     // 32768 i
#define WS_OFFS    67584     // 1025 i
#define WS_CURSOR  68612     // 1024 i
#define WS_DIFFACC 69636     // 64 f
#define WS_BESTV   69700     // 65536 f
#define WS_BESTI   135236    // 65536 i
#define WS_EHI     200772    // 131072 f16 = 65536 w
#define WS_ELO     266308    // 131072 f16
#define WS_PART    331844    // SPLIT*131072 = 262144 f
#define WS_XHI     593988    // 4194304 f16 = 2097152 w
#define WS_XLO     2691140   // 4194304 f16

typedef _Float16 f16x8 __attribute__((ext_vector_type(8)));
typedef _Float16 half4 __attribute__((ext_vector_type(4)));
typedef float    f32x4 __attribute__((ext_vector_type(4)));

// emb -> ehi/elo (f16 hi/lo split), e2; zero counts/diffacc
__global__ void vq_prep2z(const float* __restrict__ emb, float* __restrict__ e2,
                          _Float16* __restrict__ ehi, _Float16* __restrict__ elo,
                          float* __restrict__ counts, float* __restrict__ diffacc) {
    __shared__ float red[2];
    int s = blockIdx.x, d = threadIdx.x;  // 128 threads
    float v = emb[(size_t)s * TD + d];
    _Float16 h = (_Float16)v;
    ehi[(size_t)s * TD + d] = h;
    elo[(size_t)s * TD + d] = (_Float16)(v - (float)h);
    if (d == 0) counts[s] = 0.f;
    if (s < 64 && d == 1) diffacc[s] = 0.f;
    float sq = v * v;
    #pragma unroll
    for (int off = 32; off; off >>= 1) sq += __shfl_down(sq, off, 64);
    if ((d & 63) == 0) red[d >> 6] = sq;
    __syncthreads();
    if (d == 0) e2[s] = red[0] + red[1];
}

// x [B][D][T] -> xhi/xlo [N][D] f16 (transpose + hi/lo split)
__global__ void vq_xprep(const float* __restrict__ x,
                         _Float16* __restrict__ xhi, _Float16* __restrict__ xlo) {
    __shared__ float xs[64][132];     // padded, rows 16B-aligned
    const int tid = threadIdx.x;
    const int b  = blockIdx.x >> 5;
    const int tc = blockIdx.x & 31;
    const float4* x4 = (const float4*)x;
    #pragma unroll
    for (int p = 0; p < 8; p++) {
        int idx = p * 256 + tid;
        int d = idx >> 4, t4 = idx & 15;
        float4 v = x4[((size_t)b * TD + d) * 512 + tc * 16 + t4];
        xs[t4 * 4 + 0][d] = v.x;
        xs[t4 * 4 + 1][d] = v.y;
        xs[t4 * 4 + 2][d] = v.z;
        xs[t4 * 4 + 3][d] = v.w;
    }
    __syncthreads();
    const int ld = tid & 31;
    #pragma unroll
    for (int p = 0; p < 8; p++) {
        int tl = p * 8 + (tid >> 5);
        float4 v = *(const float4*)&xs[tl][ld * 4];
        half4 h, l;
        h[0] = (_Float16)v.x; l[0] = (_Float16)(v.x - (float)h[0]);
        h[1] = (_Float16)v.y; l[1] = (_Float16)(v.y - (float)h[1]);
        h[2] = (_Float16)v.z; l[2] = (_Float16)(v.z - (float)h[2]);
        h[3] = (_Float16)v.w; l[3] = (_Float16)(v.w - (float)h[3]);
        size_t n = (size_t)b * TT + tc * 64 + tl;
        *(half4*)(xhi + n * TD + ld * 4) = h;
        *(half4*)(xlo + n * TD + ld * 4) = l;
    }
}

// distance + per-half argmin. 512 blocks x 256 thr; block = 128 rows x 512 codes.
// 16x16x32 MFMA with the R4-hardware-verified fragment maps; no LDS; B from L1/L2.
__launch_bounds__(256, 2)
__global__ void vq_dist(const _Float16* __restrict__ xhi, const _Float16* __restrict__ xlo,
                        const _Float16* __restrict__ ehi, const _Float16* __restrict__ elo,
                        const float* __restrict__ e2,
                        float* __restrict__ wsV, int* __restrict__ wsI) {
    const int tid  = threadIdx.x;
    const int lane = tid & 63;
    const int wid  = tid >> 6;
    const int l15  = lane & 15;
    const int lk   = lane >> 4;        // 0..3 (k-group)
    const int split = blockIdx.x & 1;
    const int n0    = (blockIdx.x >> 1) * 128;
    const int cbase = split * 512;
    const int nrow  = n0 + wid * 32;

    // A fragments (verified map): row = lane&15, k = (lane>>4)*8 + j
    f16x8 ahi[2][4], alo[2][4];
    #pragma unroll
    for (int fr = 0; fr < 2; fr++) {
        const size_t arow = (size_t)(nrow + fr * 16 + l15);
        #pragma unroll
        for (int ks = 0; ks < 4; ks++) {
            const size_t off = arow * TD + ks * 32 + lk * 8;
            ahi[fr][ks] = *(const f16x8*)(xhi + off);
            alo[fr][ks] = *(const f16x8*)(xlo + off);
        }
    }

    float bestV[8]; int bestI[8];
    #pragma unroll
    for (int i = 0; i < 8; i++) { bestV[i] = 3.4e38f; bestI[i] = 0; }

    for (int tl = 0; tl < 8; ++tl) {
        const int c0 = cbase + tl * 64;
        f32x4 acc[2][4];
        #pragma unroll
        for (int fr = 0; fr < 2; fr++)
            #pragma unroll
            for (int fc = 0; fc < 4; fc++)
                acc[fr][fc] = (f32x4){0.f, 0.f, 0.f, 0.f};

        #pragma unroll
        for (int ks = 0; ks < 4; ks++) {
            // B fragments (verified map): col = lane&15, k = (lane>>4)*8 + j
            f16x8 bh[4], bl[4];
            #pragma unroll
            for (int fc = 0; fc < 4; fc++) {
                const size_t off = (size_t)(c0 + fc * 16 + l15) * TD + ks * 32 + lk * 8;
                bh[fc] = *(const f16x8*)(ehi + off);
                bl[fc] = *(const f16x8*)(elo + off);
            }
            #pragma unroll
            for (int fc = 0; fc < 4; fc++)
                #pragma unroll
                for (int fr = 0; fr < 2; fr++) {
                    acc[fr][fc] = __builtin_amdgcn_mfma_f32_16x16x32_f16(ahi[fr][ks], bh[fc], acc[fr][fc], 0, 0, 0);
                    acc[fr][fc] = __builtin_amdgcn_mfma_f32_16x16x32_f16(ahi[fr][ks], bl[fc], acc[fr][fc], 0, 0, 0);
                    acc[fr][fc] = __builtin_amdgcn_mfma_f32_16x16x32_f16(alo[fr][ks], bh[fc], acc[fr][fc], 0, 0, 0);
                    acc[fr][fc] = __builtin_amdgcn_mfma_f32_16x16x32_f16(alo[fr][ks], bl[fc], acc[fr][fc], 0, 0, 0);
                }
        }

        // score = e2[c] - 2*dot ; C/D (verified): col = lane&15, row = (lane>>4)*4 + reg
        float e2v[4];
        #pragma unroll
        for (int fc = 0; fc < 4; fc++) e2v[fc] = e2[c0 + fc * 16 + l15];
        #pragma unroll
        for (int fr = 0; fr < 2; fr++)
            #pragma unroll
            for (int i = 0; i < 4; i++)
                #pragma unroll
                for (int fc = 0; fc < 4; fc++) {
                    float sc = fmaf(-2.f, acc[fr][fc][i], e2v[fc]);
                    const int slot = fr * 4 + i;
                    if (sc < bestV[slot]) { bestV[slot] = sc; bestI[slot] = c0 + fc * 16 + l15; }
                }
    }

    // argmin across the 16 lanes of each lk-group (cols of each row)
    #pragma unroll
    for (int sl = 0; sl < 8; sl++) {
        #pragma unroll
        for (int m = 8; m >= 1; m >>= 1) {
            float ov = __shfl_xor(bestV[sl], m, 64);
            int   oi = __shfl_xor(bestI[sl], m, 64);
            if (ov < bestV[sl] || (ov == bestV[sl] && oi < bestI[sl])) {
                bestV[sl] = ov; bestI[sl] = oi;
            }
        }
    }
    // slot (fr,i) holds row nrow + fr*16 + lk*4 + i; lane l15==fr*4+i writes it
    #pragma unroll
    for (int fr = 0; fr < 2; fr++)
        #pragma unroll
        for (int i = 0; i < 4; i++)
            if (l15 == fr * 4 + i) {
                const int r = nrow + fr * 16 + lk * 4 + i;
                wsV[split * NROWS + r] = bestV[fr * 4 + i];
                wsI[split * NROWS + r] = bestI[fr * 4 + i];
            }
}

// merge the two code-halves, produce codes + counts
__global__ void vq_merge(const float* __restrict__ wsV, const int* __restrict__ wsI,
                         int* __restrict__ codes, float* __restrict__ counts) {
    int n = blockIdx.x * 256 + threadIdx.x;
    float v0 = wsV[n];          int i0 = wsI[n];
    float v1 = wsV[NROWS + n];  int i1 = wsI[NROWS + n];
    int best = (v1 < v0) ? i1 : i0;   // tie -> lower index (half0)
    codes[n] = best;
    atomicAdd(&counts[best], 1.0f);
}

// prefix-sum of counts -> offsets/cursor; new_usage
__global__ void vq_offsets(const float* __restrict__ usage,
                           const float* __restrict__ counts,
                           int* __restrict__ offs, int* __restrict__ cursor,
                           float* __restrict__ dout) {
    __shared__ int scan[TS];
    int i = threadIdx.x;
    int c = (int)counts[i];
    scan[i] = c;
    __syncthreads();
    for (int off = 1; off < TS; off <<= 1) {
        int v = (i >= off) ? scan[i - off] : 0;
        __syncthreads();
        scan[i] += v;
        __syncthreads();
    }
    int excl = scan[i] - c;
    offs[i] = excl;
    cursor[i] = excl;
    if (i == TS - 1) offs[TS] = scan[i];
    dout[OFF_USAGE + i] = EMA_W * usage[i] + (1.0f - EMA_W) * counts[i];
}

__global__ void vq_scatteridx(const int* __restrict__ codes,
                              int* __restrict__ cursor, int* __restrict__ rowlist) {
    int n = blockIdx.x * 256 + threadIdx.x;
    int c = codes[n];
    int pos = atomicAdd(&cursor[c], 1);
    rowlist[pos] = n;
}

// quantized write + diff partials (pure memory-bound, full occupancy)
__global__ void vq_epi(const float* __restrict__ x, const float* __restrict__ emb,
                       const int* __restrict__ codes,
                       float* __restrict__ dout, float* __restrict__ diffacc) {
    float local = 0.f;
    const float4* x4 = (const float4*)x;
    float4* out4 = (float4*)(dout + OFF_Q);
    #pragma unroll
    for (int p = 0; p < 2; p++) {
        int idx = blockIdx.x * 512 + p * 256 + threadIdx.x;  // over 2048 rows x 512 f4
        int row = idx >> 9, t4 = idx & 511;
        int d = row & 127;
        int nb = (row >> 7) * TT + t4 * 4;
        int4 c4 = *(const int4*)(codes + nb);
        float4 xv = x4[(size_t)row * 512 + t4];
        float4 q;
        q.x = emb[(size_t)c4.x * TD + d];
        q.y = emb[(size_t)c4.y * TD + d];
        q.z = emb[(size_t)c4.z * TD + d];
        q.w = emb[(size_t)c4.w * TD + d];
        out4[(size_t)row * 512 + t4] = q;
        float dx = xv.x - q.x; local = fmaf(dx, dx, local);
        dx = xv.y - q.y; local = fmaf(dx, dx, local);
        dx = xv.z - q.z; local = fmaf(dx, dx, local);
        dx = xv.w - q.w; local = fmaf(dx, dx, local);
    }
    #pragma unroll
    for (int off = 32; off; off >>= 1) local += __shfl_down(local, off, 64);
    if ((threadIdx.x & 63) == 0) atomicAdd(&diffacc[blockIdx.x & 63], local);
}

// gather-sum from xhi/xlo: SPLIT blocks per code x 1024 thr (8 row-groups x 128 dims)
__global__ void vq_sum2(const _Float16* __restrict__ xhi, const _Float16* __restrict__ xlo,
                        const int* __restrict__ offs, const int* __restrict__ rowlist,
                        float* __restrict__ part) {
    const int s  = blockIdx.x >> 1;
    const int sp = blockIdx.x & 1;
    const int g  = threadIdx.x >> 7;
    const int d  = threadIdx.x & 127;
    const int beg = offs[s], end = offs[s + 1];
    const int stride = SPLIT * 8;      // 16 rows in flight per code

    float a0 = 0.f, a1 = 0.f;
    int i = beg + sp * 8 + g;
    for (; i + stride < end; i += 2 * stride) {
        int n0 = rowlist[i];
        int n1 = rowlist[i + stride];
        a0 += (float)xhi[(size_t)n0 * TD + d] + (float)xlo[(size_t)n0 * TD + d];
        a1 += (float)xhi[(size_t)n1 * TD + d] + (float)xlo[(size_t)n1 * TD + d];
    }
    if (i < end) {
        int n0 = rowlist[i];
        a0 += (float)xhi[(size_t)n0 * TD + d] + (float)xlo[(size_t)n0 * TD + d];
    }
    float v = a0 + a1;

    __shared__ float red[1024];
    red[threadIdx.x] = v;
    __syncthreads();
    if (threadIdx.x < 512) red[threadIdx.x] += red[threadIdx.x + 512];
    __syncthreads();
    if (threadIdx.x < 256) red[threadIdx.x] += red[threadIdx.x + 256];
    __syncthreads();
    if (threadIdx.x < 128)
        part[(size_t)sp * (TS * TD) + (size_t)s * TD + d]
            = red[threadIdx.x] + red[threadIdx.x + 128];
}

// finalize: sum partials -> EMA embedding; diff scalar
__global__ void vq_fin(const float* __restrict__ emb,
                       const float* __restrict__ counts,
                       const float* __restrict__ part,
                       const float* __restrict__ diffacc,
                       float* __restrict__ dout) {
    int g = blockIdx.x * 256 + threadIdx.x;  // 0..131071
    int s = g >> 7;
    float sum = part[g] + part[TS * TD + g];
    float cnt = counts[s];
    float e = emb[g];
    float tgt = (cnt > 0.f) ? (sum / cnt) : e;
    dout[OFF_EMB + g] = EMA_W * e + (1.0f - EMA_W) * tgt;
    if (blockIdx.x == 0 && threadIdx.x < 64) {
        float v = diffacc[threadIdx.x];
        #pragma unroll
        for (int off = 32; off; off >>= 1) v += __shfl_down(v, off, 64);
        if (threadIdx.x == 0)
            dout[OFF_DIFF] = v * (1.0f / ((float)NROWS * (float)TD));
    }
}

extern "C" void kernel_launch(void* const* d_in, const int* in_sizes, int n_in,
                              void* d_out, int out_size, void* d_ws, size_t ws_size,
                              hipStream_t stream) {
    const float* x     = (const float*)d_in[0];
    const float* emb   = (const float*)d_in[1];
    const float* usage = (const float*)d_in[2];
    float* dout = (float*)d_out;

    float* wsf = (float*)d_ws;
    int*   wsi = (int*)d_ws;
    float* e2      = wsf + WS_E2;
    float* counts  = wsf + WS_COUNTS;
    int*   codes   = wsi + WS_CODES;
    int*   rowlist = wsi + WS_ROWLIST;
    int*   offs    = wsi + WS_OFFS;
    int*   cursor  = wsi + WS_CURSOR;
    float* diffacc = wsf + WS_DIFFACC;
    float* wsV     = wsf + WS_BESTV;
    int*   wsI     = wsi + WS_BESTI;
    _Float16* ehi  = (_Float16*)(wsf + WS_EHI);
    _Float16* elo  = (_Float16*)(wsf + WS_ELO);
    float* part    = wsf + WS_PART;
    _Float16* xhi  = (_Float16*)(wsf + WS_XHI);
    _Float16* xlo  = (_Float16*)(wsf + WS_XLO);

    vq_prep2z<<<TS, TD, 0, stream>>>(emb, e2, ehi, elo, counts, diffacc);
    vq_xprep<<<512, 256, 0, stream>>>(x, xhi, xlo);
    vq_dist<<<512, 256, 0, stream>>>(xhi, xlo, ehi, elo, e2, wsV, wsI);
    vq_merge<<<NROWS / 256, 256, 0, stream>>>(wsV, wsI, codes, counts);
    vq_offsets<<<1, TS, 0, stream>>>(usage, counts, offs, cursor, dout);
    vq_scatteridx<<<NROWS / 256, 256, 0, stream>>>(codes, cursor, rowlist);
    vq_epi<<<2048, 256, 0, stream>>>(x, emb, codes, dout, diffacc);
    vq_sum2<<<TS * SPLIT, 1024, 0, stream>>>(xhi, xlo, offs, rowlist, part);
    vq_fin<<<(TS * TD) / 256, 256, 0, stream>>>(emb, counts, part, diffacc, dout);
}

// Round 7
// 213.309 us; speedup vs baseline: 1.0212x; 1.0212x over previous
//
#include <hip/hip_runtime.h>

// Problem constants
#define TD 128        // D
#define TS 1024       // SIZE (codes)
#define TT 2048       // T
#define NROWS 32768   // B*T
#define NSPLIT 4      // code-splits in vq_dist (occupancy) and vq_sum2
#define EMA_W 0.99f

// d_out layout (flat fp32): [quantized BxDxT][diff][new_embedding SxD][new_usage S]
#define OFF_Q     0
#define OFF_DIFF  4194304
#define OFF_EMB   4194305
#define OFF_USAGE 4325377

// ws layout (units: 4-byte words). End = 4,788,292 words = 19.15 MB
// < proven ws_size lower bound 19.68 MB (R4 ran its xf path at 19,677,200 B).
#define WS_E2      0         // 1024 f
#define WS_COUNTS  1024      // 1024 f
#define WS_CODES   2048      // 32768 i
#define WS_ROWLIST 34816     // 32768 i
#define WS_OFFS    67584     // 1025 i
#define WS_CURSOR  68612     // 1024 i
#define WS_DIFFACC 69636     // 64 f
#define WS_BESTV   69700     // 4*32768 f
#define WS_BESTI   200772    // 4*32768 i
#define WS_EHI     331844    // 131072 f16 = 65536 w
#define WS_ELO     397380    // 131072 f16
#define WS_PART    462916    // 131072 f (single copy, atomic-accumulated)
#define WS_XHI     593988    // 4194304 f16 = 2097152 w
#define WS_XLO     2691140   // 4194304 f16  -> end 4788292

typedef _Float16 f16x8 __attribute__((ext_vector_type(8)));
typedef _Float16 half4 __attribute__((ext_vector_type(4)));
typedef float    f32x4 __attribute__((ext_vector_type(4)));

// emb -> ehi/elo (f16 hi/lo split), e2; zero counts/diffacc/part
__global__ void vq_prep2z(const float* __restrict__ emb, float* __restrict__ e2,
                          _Float16* __restrict__ ehi, _Float16* __restrict__ elo,
                          float* __restrict__ counts, float* __restrict__ diffacc,
                          float* __restrict__ part) {
    __shared__ float red[2];
    int s = blockIdx.x, d = threadIdx.x;  // 128 threads
    float v = emb[(size_t)s * TD + d];
    _Float16 h = (_Float16)v;
    ehi[(size_t)s * TD + d] = h;
    elo[(size_t)s * TD + d] = (_Float16)(v - (float)h);
    part[(size_t)s * TD + d] = 0.f;
    if (d == 0) counts[s] = 0.f;
    if (s < 64 && d == 1) diffacc[s] = 0.f;
    float sq = v * v;
    #pragma unroll
    for (int off = 32; off; off >>= 1) sq += __shfl_down(sq, off, 64);
    if ((d & 63) == 0) red[d >> 6] = sq;
    __syncthreads();
    if (d == 0) e2[s] = red[0] + red[1];
}

// x [B][D][T] -> xhi/xlo [N][D] f16 (transpose + hi/lo split)
__global__ void vq_xprep(const float* __restrict__ x,
                         _Float16* __restrict__ xhi, _Float16* __restrict__ xlo) {
    __shared__ float xs[64][132];     // padded, rows 16B-aligned
    const int tid = threadIdx.x;
    const int b  = blockIdx.x >> 5;
    const int tc = blockIdx.x & 31;
    const float4* x4 = (const float4*)x;
    #pragma unroll
    for (int p = 0; p < 8; p++) {
        int idx = p * 256 + tid;
        int d = idx >> 4, t4 = idx & 15;
        float4 v = x4[((size_t)b * TD + d) * 512 + tc * 16 + t4];
        xs[t4 * 4 + 0][d] = v.x;
        xs[t4 * 4 + 1][d] = v.y;
        xs[t4 * 4 + 2][d] = v.z;
        xs[t4 * 4 + 3][d] = v.w;
    }
    __syncthreads();
    const int ld = tid & 31;
    #pragma unroll
    for (int p = 0; p < 8; p++) {
        int tl = p * 8 + (tid >> 5);
        float4 v = *(const float4*)&xs[tl][ld * 4];
        half4 h, l;
        h[0] = (_Float16)v.x; l[0] = (_Float16)(v.x - (float)h[0]);
        h[1] = (_Float16)v.y; l[1] = (_Float16)(v.y - (float)h[1]);
        h[2] = (_Float16)v.z; l[2] = (_Float16)(v.z - (float)h[2]);
        h[3] = (_Float16)v.w; l[3] = (_Float16)(v.w - (float)h[3]);
        size_t n = (size_t)b * TT + tc * 64 + tl;
        *(half4*)(xhi + n * TD + ld * 4) = h;
        *(half4*)(xlo + n * TD + ld * 4) = l;
    }
}

// distance + per-split argmin. 1024 blocks x 256 thr; block = 128 rows x 256 codes.
// 16x16x32 MFMA, R4/R6-verified fragment maps; no LDS; B from L1/L2.
// 3-term hi/lo product (al*bl dropped: |err| ~ 7e-7, below fp32 accum noise).
__launch_bounds__(256, 4)
__global__ void vq_dist(const _Float16* __restrict__ xhi, const _Float16* __restrict__ xlo,
                        const _Float16* __restrict__ ehi, const _Float16* __restrict__ elo,
                        const float* __restrict__ e2,
                        float* __restrict__ wsV, int* __restrict__ wsI) {
    const int tid  = threadIdx.x;
    const int lane = tid & 63;
    const int wid  = tid >> 6;
    const int l15  = lane & 15;
    const int lk   = lane >> 4;        // 0..3 (k-group)
    const int split = blockIdx.x & 3;
    const int n0    = (blockIdx.x >> 2) * 128;
    const int cbase = split * 256;
    const int nrow  = n0 + wid * 32;

    // A fragments (verified map): row = lane&15, k = (lane>>4)*8 + j
    f16x8 ahi[2][4], alo[2][4];
    #pragma unroll
    for (int fr = 0; fr < 2; fr++) {
        const size_t arow = (size_t)(nrow + fr * 16 + l15);
        #pragma unroll
        for (int ks = 0; ks < 4; ks++) {
            const size_t off = arow * TD + ks * 32 + lk * 8;
            ahi[fr][ks] = *(const f16x8*)(xhi + off);
            alo[fr][ks] = *(const f16x8*)(xlo + off);
        }
    }

    float bestV[8]; int bestI[8];
    #pragma unroll
    for (int i = 0; i < 8; i++) { bestV[i] = 3.4e38f; bestI[i] = 0; }

    #pragma unroll
    for (int tl = 0; tl < 4; ++tl) {
        const int c0 = cbase + tl * 64;
        f32x4 acc[2][4];
        #pragma unroll
        for (int fr = 0; fr < 2; fr++)
            #pragma unroll
            for (int fc = 0; fc < 4; fc++)
                acc[fr][fc] = (f32x4){0.f, 0.f, 0.f, 0.f};

        #pragma unroll
        for (int ks = 0; ks < 4; ks++) {
            // B fragments (verified map): col = lane&15, k = (lane>>4)*8 + j
            f16x8 bh[4], bl[4];
            #pragma unroll
            for (int fc = 0; fc < 4; fc++) {
                const size_t off = (size_t)(c0 + fc * 16 + l15) * TD + ks * 32 + lk * 8;
                bh[fc] = *(const f16x8*)(ehi + off);
                bl[fc] = *(const f16x8*)(elo + off);
            }
            #pragma unroll
            for (int fc = 0; fc < 4; fc++)
                #pragma unroll
                for (int fr = 0; fr < 2; fr++) {
                    acc[fr][fc] = __builtin_amdgcn_mfma_f32_16x16x32_f16(ahi[fr][ks], bh[fc], acc[fr][fc], 0, 0, 0);
                    acc[fr][fc] = __builtin_amdgcn_mfma_f32_16x16x32_f16(ahi[fr][ks], bl[fc], acc[fr][fc], 0, 0, 0);
                    acc[fr][fc] = __builtin_amdgcn_mfma_f32_16x16x32_f16(alo[fr][ks], bh[fc], acc[fr][fc], 0, 0, 0);
                }
        }

        // score = e2[c] - 2*dot ; C/D (verified): col = lane&15, row = (lane>>4)*4 + reg
        float e2v[4];
        #pragma unroll
        for (int fc = 0; fc < 4; fc++) e2v[fc] = e2[c0 + fc * 16 + l15];
        #pragma unroll
        for (int fr = 0; fr < 2; fr++)
            #pragma unroll
            for (int i = 0; i < 4; i++)
                #pragma unroll
                for (int fc = 0; fc < 4; fc++) {
                    float sc = fmaf(-2.f, acc[fr][fc][i], e2v[fc]);
                    const int slot = fr * 4 + i;
                    if (sc < bestV[slot]) { bestV[slot] = sc; bestI[slot] = c0 + fc * 16 + l15; }
                }
    }

    // argmin across the 16 lanes of each lk-group (cols of each row)
    #pragma unroll
    for (int sl = 0; sl < 8; sl++) {
        #pragma unroll
        for (int m = 8; m >= 1; m >>= 1) {
            float ov = __shfl_xor(bestV[sl], m, 64);
            int   oi = __shfl_xor(bestI[sl], m, 64);
            if (ov < bestV[sl] || (ov == bestV[sl] && oi < bestI[sl])) {
                bestV[sl] = ov; bestI[sl] = oi;
            }
        }
    }
    // slot (fr,i) holds row nrow + fr*16 + lk*4 + i; lane l15==fr*4+i writes it
    #pragma unroll
    for (int fr = 0; fr < 2; fr++)
        #pragma unroll
        for (int i = 0; i < 4; i++)
            if (l15 == fr * 4 + i) {
                const int r = nrow + fr * 16 + lk * 4 + i;
                wsV[split * NROWS + r] = bestV[fr * 4 + i];
                wsI[split * NROWS + r] = bestI[fr * 4 + i];
            }
}

// merge the four code-splits, produce codes + counts
__global__ void vq_merge(const float* __restrict__ wsV, const int* __restrict__ wsI,
                         int* __restrict__ codes, float* __restrict__ counts) {
    int n = blockIdx.x * 256 + threadIdx.x;
    float bv = wsV[n]; int bi = wsI[n];
    #pragma unroll
    for (int s = 1; s < NSPLIT; s++) {
        float v = wsV[s * NROWS + n];
        int   i = wsI[s * NROWS + n];
        if (v < bv) { bv = v; bi = i; }  // strict < : splits ordered by code range -> first-index tie-break
    }
    codes[n] = bi;
    atomicAdd(&counts[bi], 1.0f);
}

// shfl-based scan of counts -> offsets/cursor; new_usage
__global__ void vq_offsets(const float* __restrict__ usage,
                           const float* __restrict__ counts,
                           int* __restrict__ offs, int* __restrict__ cursor,
                           float* __restrict__ dout) {
    __shared__ int wsums[16];
    int i = threadIdx.x;               // one block of 1024 = 16 waves
    int lane = i & 63, wid = i >> 6;
    int c = (int)counts[i];
    int v = c;
    #pragma unroll
    for (int off = 1; off < 64; off <<= 1) {
        int t = __shfl_up(v, off, 64);
        if (lane >= off) v += t;
    }
    if (lane == 63) wsums[wid] = v;
    __syncthreads();
    if (i < 16) {
        int w = wsums[i];
        #pragma unroll
        for (int off = 1; off < 16; off <<= 1) {
            int t = __shfl_up(w, off, 64);
            if (i >= off) w += t;
        }
        wsums[i] = w;
    }
    __syncthreads();
    int incl = v + (wid ? wsums[wid - 1] : 0);
    int excl = incl - c;
    offs[i] = excl;
    cursor[i] = excl;
    if (i == TS - 1) offs[TS] = incl;
    dout[OFF_USAGE + i] = EMA_W * usage[i] + (1.0f - EMA_W) * counts[i];
}

__global__ void vq_scatteridx(const int* __restrict__ codes,
                              int* __restrict__ cursor, int* __restrict__ rowlist) {
    int n = blockIdx.x * 256 + threadIdx.x;
    int c = codes[n];
    int pos = atomicAdd(&cursor[c], 1);
    rowlist[pos] = n;
}

// quantized write + diff. Thread = (b, 4 dims, 4 t's): emb gathers are float4.
__global__ void vq_epi(const float* __restrict__ x, const float* __restrict__ emb,
                       const int* __restrict__ codes,
                       float* __restrict__ dout, float* __restrict__ diffacc) {
    const int idx  = blockIdx.x * 256 + threadIdx.x;  // 0..262143
    const int row4 = idx >> 9;         // 0..511 = (b, d-quad)
    const int t4   = idx & 511;
    const int b    = row4 >> 5;
    const int d0q  = row4 & 31;        // d0 = d0q*4
    const int nb   = b * TT + t4 * 4;
    const int4 c4 = *(const int4*)(codes + nb);
    const float4* x4p = (const float4*)x;
    const float4* e4p = (const float4*)emb;
    float4* out4 = (float4*)(dout + OFF_Q);
    const float4 e0 = e4p[(size_t)c4.x * 32 + d0q];
    const float4 e1 = e4p[(size_t)c4.y * 32 + d0q];
    const float4 e2v = e4p[(size_t)c4.z * 32 + d0q];
    const float4 e3 = e4p[(size_t)c4.w * 32 + d0q];
    float local = 0.f;
#define EPI_STEP(J, C0, C1, C2, C3) { \
        size_t plane = ((size_t)b * TD + d0q * 4 + J) * 512 + t4; \
        float4 xv = x4p[plane]; \
        float4 q = make_float4(C0, C1, C2, C3); \
        out4[plane] = q; \
        float dx = xv.x - q.x; local = fmaf(dx, dx, local); \
        dx = xv.y - q.y; local = fmaf(dx, dx, local); \
        dx = xv.z - q.z; local = fmaf(dx, dx, local); \
        dx = xv.w - q.w; local = fmaf(dx, dx, local); }
    EPI_STEP(0, e0.x, e1.x, e2v.x, e3.x)
    EPI_STEP(1, e0.y, e1.y, e2v.y, e3.y)
    EPI_STEP(2, e0.z, e1.z, e2v.z, e3.z)
    EPI_STEP(3, e0.w, e1.w, e2v.w, e3.w)
#undef EPI_STEP
    #pragma unroll
    for (int off = 32; off; off >>= 1) local += __shfl_down(local, off, 64);
    if ((threadIdx.x & 63) == 0) atomicAdd(&diffacc[blockIdx.x & 63], local);
}

// gather-sum from xhi/xlo: NSPLIT blocks per code x 1024 thr (8 row-groups x 128 dims);
// partials accumulated into the single `part` copy via fp32 atomics (pre-zeroed).
__global__ void vq_sum2(const _Float16* __restrict__ xhi, const _Float16* __restrict__ xlo,
                        const int* __restrict__ offs, const int* __restrict__ rowlist,
                        float* __restrict__ part) {
    const int s  = blockIdx.x >> 2;
    const int sp = blockIdx.x & 3;
    const int g  = threadIdx.x >> 7;
    const int d  = threadIdx.x & 127;
    const int beg = offs[s], end = offs[s + 1];
    const int stride = NSPLIT * 8;     // 32 rows in flight per code

    float a0 = 0.f, a1 = 0.f;
    int i = beg + sp * 8 + g;
    for (; i + stride < end; i += 2 * stride) {
        int n0 = rowlist[i];
        int n1 = rowlist[i + stride];
        a0 += (float)xhi[(size_t)n0 * TD + d] + (float)xlo[(size_t)n0 * TD + d];
        a1 += (float)xhi[(size_t)n1 * TD + d] + (float)xlo[(size_t)n1 * TD + d];
    }
    if (i < end) {
        int n0 = rowlist[i];
        a0 += (float)xhi[(size_t)n0 * TD + d] + (float)xlo[(size_t)n0 * TD + d];
    }
    float v = a0 + a1;

    __shared__ float red[1024];
    red[threadIdx.x] = v;
    __syncthreads();
    if (threadIdx.x < 512) red[threadIdx.x] += red[threadIdx.x + 512];
    __syncthreads();
    if (threadIdx.x < 256) red[threadIdx.x] += red[threadIdx.x + 256];
    __syncthreads();
    if (threadIdx.x < 128) {
        float p = red[threadIdx.x] + red[threadIdx.x + 128];
        atomicAdd(&part[(size_t)s * TD + d], p);
    }
}

// finalize: part -> EMA embedding; diff scalar
__global__ void vq_fin(const float* __restrict__ emb,
                       const float* __restrict__ counts,
                       const float* __restrict__ part,
                       const float* __restrict__ diffacc,
                       float* __restrict__ dout) {
    int g = blockIdx.x * 256 + threadIdx.x;  // 0..131071
    int s = g >> 7;
    float sum = part[g];
    float cnt = counts[s];
    float e = emb[g];
    float tgt = (cnt > 0.f) ? (sum / cnt) : e;
    dout[OFF_EMB + g] = EMA_W * e + (1.0f - EMA_W) * tgt;
    if (blockIdx.x == 0 && threadIdx.x < 64) {
        float v = diffacc[threadIdx.x];
        #pragma unroll
        for (int off = 32; off; off >>= 1) v += __shfl_down(v, off, 64);
        if (threadIdx.x == 0)
            dout[OFF_DIFF] = v * (1.0f / ((float)NROWS * (float)TD));
    }
}

extern "C" void kernel_launch(void* const* d_in, const int* in_sizes, int n_in,
                              void* d_out, int out_size, void* d_ws, size_t ws_size,
                              hipStream_t stream) {
    const float* x     = (const float*)d_in[0];
    const float* emb   = (const float*)d_in[1];
    const float* usage = (const float*)d_in[2];
    float* dout = (float*)d_out;

    float* wsf = (float*)d_ws;
    int*   wsi = (int*)d_ws;
    float* e2      = wsf + WS_E2;
    float* counts  = wsf + WS_COUNTS;
    int*   codes   = wsi + WS_CODES;
    int*   rowlist = wsi + WS_ROWLIST;
    int*   offs    = wsi + WS_OFFS;
    int*   cursor  = wsi + WS_CURSOR;
    float* diffacc = wsf + WS_DIFFACC;
    float* wsV     = wsf + WS_BESTV;
    int*   wsI     = wsi + WS_BESTI;
    _Float16* ehi  = (_Float16*)(wsf + WS_EHI);
    _Float16* elo  = (_Float16*)(wsf + WS_ELO);
    float* part    = wsf + WS_PART;
    _Float16* xhi  = (_Float16*)(wsf + WS_XHI);
    _Float16* xlo  = (_Float16*)(wsf + WS_XLO);

    vq_prep2z<<<TS, TD, 0, stream>>>(emb, e2, ehi, elo, counts, diffacc, part);
    vq_xprep<<<512, 256, 0, stream>>>(x, xhi, xlo);
    vq_dist<<<(NROWS / 128) * NSPLIT, 256, 0, stream>>>(xhi, xlo, ehi, elo, e2, wsV, wsI);
    vq_merge<<<NROWS / 256, 256, 0, stream>>>(wsV, wsI, codes, counts);
    vq_offsets<<<1, TS, 0, stream>>>(usage, counts, offs, cursor, dout);
    vq_scatteridx<<<NROWS / 256, 256, 0, stream>>>(codes, cursor, rowlist);
    vq_epi<<<1024, 256, 0, stream>>>(x, emb, codes, dout, diffacc);
    vq_sum2<<<TS * NSPLIT, 1024, 0, stream>>>(xhi, xlo, offs, rowlist, part);
    vq_fin<<<(TS * TD) / 256, 256, 0, stream>>>(emb, counts, part, diffacc, dout);
}